// Round 6
// baseline (722.589 us; speedup 1.0000x reference)
//
#include <hip/hip_runtime.h>
#include <hip/hip_bf16.h>
#include <math.h>
#include <stdint.h>

#define D_    1024
#define DI_   2048
#define DS_   16
#define DTR_  64
#define B_    2
#define L_    4096
#define ROWS_ 8192
#define NXZ_  4096

typedef __attribute__((ext_vector_type(8))) __bf16 bf16x8;
typedef __attribute__((ext_vector_type(4))) float  f32x4;

__device__ __forceinline__ unsigned short f2bf(float f) {
    unsigned u = __float_as_uint(f);
    unsigned r = (u + 0x7fffu + ((u >> 16) & 1u)) >> 16;   // RNE
    return (unsigned short)r;
}
__device__ __forceinline__ float bf2f(unsigned short h) {
    return __uint_as_float(((unsigned)h) << 16);
}

// direct global->LDS 16B load (dest = wave-uniform base + lane*16)
__device__ __forceinline__ void gload16(const void* gp, void* lp) {
    auto* g1 = (const __attribute__((address_space(1))) unsigned int*)(uintptr_t)gp;
    auto* l3 = (__attribute__((address_space(3))) unsigned int*)(uintptr_t)lp;
    __builtin_amdgcn_global_load_lds(g1, l3, 16, 0, 0);
}

// ---------------------------------------------------------------------------
// cvt: fp32 -> bf16, same layout (for x)
// ---------------------------------------------------------------------------
__global__ __launch_bounds__(256) void kcvt(const float* __restrict__ in,
                                            unsigned short* __restrict__ out) {
    const int i = blockIdx.x * 256 + threadIdx.x;   // float4 index
    const float4 v = ((const float4*)in)[i];
    ushort4 o;
    o.x = f2bf(v.x); o.y = f2bf(v.y); o.z = f2bf(v.z); o.w = f2bf(v.w);
    ((ushort4*)out)[i] = o;
}

// ---------------------------------------------------------------------------
// transpose + cvt + col-pad: W [R][Csrc] f32 -> WT [gridDim.x*32][R] bf16
// ---------------------------------------------------------------------------
__global__ __launch_bounds__(256) void ktrans(const float* __restrict__ W,
                                              unsigned short* __restrict__ WT,
                                              int R, int Csrc) {
    __shared__ float tile[32][33];
    const int c0 = blockIdx.x * 32, r0 = blockIdx.y * 32;
    const int tc = threadIdx.x & 31, tr = threadIdx.x >> 5;   // tr: 0..7
#pragma unroll
    for (int i = 0; i < 32; i += 8)
        tile[tr + i][tc] = (c0 + tc < Csrc)
                           ? W[(size_t)(r0 + tr + i) * Csrc + c0 + tc] : 0.f;
    __syncthreads();
#pragma unroll
    for (int i = 0; i < 32; i += 8)
        WT[(size_t)(c0 + tr + i) * R + r0 + tc] = f2bf(tile[tc][tr + i]);
}

// ---------------------------------------------------------------------------
// gemm256: 256x256 tile, BK=64, 8 waves (2Mx4N), 8-phase schedule with
// counted vmcnt (T3+T4), chunk-XOR LDS swizzle (T2), setprio (T5),
// XCD swizzle (T1). A [M][K] bf16, B [N][K] bf16. bf16 out.
// ---------------------------------------------------------------------------
#define MFMA_Q(MB, NB)                                                          \
    _Pragma("unroll")                                                           \
    for (int m_ = 0; m_ < 4; ++m_) {                                            \
        _Pragma("unroll")                                                       \
        for (int n_ = 0; n_ < 2; ++n_) {                                        \
            _Pragma("unroll")                                                   \
            for (int kk_ = 0; kk_ < 2; ++kk_)                                   \
                acc[MB + m_][NB + n_] = __builtin_amdgcn_mfma_f32_16x16x32_bf16( \
                    a[m_][kk_], b[NB + n_][kk_], acc[MB + m_][NB + n_], 0, 0, 0);\
        }                                                                       \
    }

// One K-tile = 4 phases. Stages one half-tile per phase (guarded), counted
// vmcnt per VMODE (1 -> vmcnt(4), 2 -> vmcnt(0), 0 -> none) in phase 4.
#define KTILE(BUF, KT1, W1, KT2, W2, KT3, W3, KT4, W4, VMODE)                   \
    _Pragma("unroll")                                                           \
    for (int m_ = 0; m_ < 4; ++m_) { a[m_][0] = lda(BUF, m_, 0);                \
                                     a[m_][1] = lda(BUF, m_, 1); }              \
    _Pragma("unroll")                                                           \
    for (int n_ = 0; n_ < 2; ++n_) { b[n_][0] = ldb(BUF, n_, 0);                \
                                     b[n_][1] = ldb(BUF, n_, 1); }              \
    stage_ht(KT1, W1);                                                          \
    __builtin_amdgcn_s_barrier();                                               \
    __builtin_amdgcn_s_setprio(1); MFMA_Q(0, 0); __builtin_amdgcn_s_setprio(0); \
    __builtin_amdgcn_s_barrier();                                               \
    _Pragma("unroll")                                                           \
    for (int n_ = 2; n_ < 4; ++n_) { b[n_][0] = ldb(BUF, n_, 0);                \
                                     b[n_][1] = ldb(BUF, n_, 1); }              \
    stage_ht(KT2, W2);                                                          \
    __builtin_amdgcn_s_barrier();                                               \
    __builtin_amdgcn_s_setprio(1); MFMA_Q(0, 2); __builtin_amdgcn_s_setprio(0); \
    __builtin_amdgcn_s_barrier();                                               \
    _Pragma("unroll")                                                           \
    for (int m_ = 0; m_ < 4; ++m_) { a[m_][0] = lda(BUF, 4 + m_, 0);            \
                                     a[m_][1] = lda(BUF, 4 + m_, 1); }          \
    stage_ht(KT3, W3);                                                          \
    __builtin_amdgcn_s_barrier();                                               \
    __builtin_amdgcn_s_setprio(1); MFMA_Q(4, 0); __builtin_amdgcn_s_setprio(0); \
    __builtin_amdgcn_s_barrier();                                               \
    stage_ht(KT4, W4);                                                          \
    if ((VMODE) == 1) { asm volatile("s_waitcnt vmcnt(4)" ::: "memory"); }      \
    if ((VMODE) == 2) { asm volatile("s_waitcnt vmcnt(0)" ::: "memory"); }      \
    __builtin_amdgcn_s_barrier();                                               \
    __builtin_amdgcn_s_setprio(1); MFMA_Q(4, 2); __builtin_amdgcn_s_setprio(0); \
    __builtin_amdgcn_s_barrier();

template <int K>
__global__ __launch_bounds__(512, 1) void gemm256(const unsigned short* __restrict__ A,
                                                  const unsigned short* __restrict__ Bm,
                                                  unsigned short* __restrict__ C, int ldc) {
    constexpr int NT = K / 64;
    const int t = threadIdx.x;
    const int wid = t >> 6, lane = t & 63;
    const int l15 = lane & 15, g = lane >> 4;
    // T1: XCD-aware bijective swizzle (nwg % 8 == 0)
    const int gx = gridDim.x, nwg = gx * gridDim.y;
    int lin = blockIdx.y * gx + blockIdx.x;
    lin = (lin & 7) * (nwg >> 3) + (lin >> 3);
    const int m0 = (lin % gx) * 256;
    const int n0 = (lin / gx) * 256;
    const int wr = wid >> 2, wc = wid & 3;

    __shared__ unsigned short lds[65536];   // 128 KB: A dbuf 2x16KB, B dbuf 2x16KB (x2 halves)

    // staging geometry: per gload16 instruction j, this thread covers 16B chunk
    // p = (wid*2+j)*64 + lane of a 128x64 half-tile (1024 chunks).
    int pr[2], ps[2];
#pragma unroll
    for (int j = 0; j < 2; ++j) {
        const int p = (wid * 2 + j) * 64 + lane;
        pr[j] = p >> 3;                       // row 0..127 within half
        ps[j] = (p & 7) ^ (pr[j] & 7);        // T2 inverse-swizzled source slab
    }
    auto stage_ht = [&](int kt, int which) {  // which: 0=A0 1=A1 2=B0 3=B1
        if (kt >= NT) return;
        const int buf = kt & 1;
        const int half = which & 1;
        const bool isB = which >= 2;
        const unsigned short* src = isB ? Bm : A;
        const int row0 = isB ? n0 : m0;
        const int base_byte = (isB ? 65536 : 0) + buf * 32768 + half * 16384;
#pragma unroll
        for (int j = 0; j < 2; ++j)
            gload16(src + (size_t)(row0 + half * 128 + pr[j]) * K + kt * 64 + ps[j] * 8,
                    (char*)lds + base_byte + (wid * 2 + j) * 1024);
    };
    // swizzled ds_read of one bf16x8 fragment
    auto lda = [&](int buf, int m, int kk) -> bf16x8 {
        const int R = wr * 128 + m * 16 + l15;
        const int S = kk * 4 + g;
        return *(const bf16x8*)&lds[buf * 16384 + R * 64 + ((S ^ (l15 & 7)) << 3)];
    };
    auto ldb = [&](int buf, int n, int kk) -> bf16x8 {
        const int R = wc * 64 + n * 16 + l15;
        const int S = kk * 4 + g;
        return *(const bf16x8*)&lds[32768 + buf * 16384 + R * 64 + ((S ^ (l15 & 7)) << 3)];
    };

    f32x4 acc[8][4];
    const f32x4 z4 = {0.f, 0.f, 0.f, 0.f};
#pragma unroll
    for (int m = 0; m < 8; ++m)
#pragma unroll
        for (int n = 0; n < 4; ++n) acc[m][n] = z4;
    bf16x8 a[4][2], b[4][2];

    // prologue: c0 fully, then c1.B0, c1.A0; wait for c0 (allow 2 ht in flight)
    stage_ht(0, 2); stage_ht(0, 0); stage_ht(0, 1); stage_ht(0, 3);
    stage_ht(1, 2); stage_ht(1, 0);
    asm volatile("s_waitcnt vmcnt(4)" ::: "memory");
    __builtin_amdgcn_s_barrier();

    for (int it = 0; it < NT / 2; ++it) {
        const int c = 2 * it;
        if (it < NT / 2 - 1) {
            KTILE(0, c + 1, 1, c + 1, 3, c + 2, 2, c + 2, 0, 1)
            KTILE(1, c + 2, 1, c + 2, 3, c + 3, 2, c + 3, 0, 1)
        } else {
            KTILE(0, c + 1, 1, c + 1, 3, NT, 2, NT, 0, 2)
            KTILE(1, NT, 1, NT, 3, NT, 2, NT, 0, 0)
        }
    }

    const int crow = g * 4;
#pragma unroll
    for (int m = 0; m < 8; ++m)
#pragma unroll
        for (int n = 0; n < 4; ++n)
#pragma unroll
            for (int j = 0; j < 4; ++j)
                C[(size_t)(m0 + wr * 128 + m * 16 + crow + j) * ldc +
                  (n0 + wc * 64 + n * 16 + l15)] = f2bf(acc[m][n][j]);
}

// ---------------------------------------------------------------------------
// bf16 MFMA GEMM, 128x128 tile, BK=64, 4 waves, 2-barrier loop + XCD swizzle.
// ---------------------------------------------------------------------------
template <int K, bool BF16OUT>
__global__ __launch_bounds__(256, 3) void gemm_bf16(const unsigned short* __restrict__ A,
                                                    const unsigned short* __restrict__ B,
                                                    void* __restrict__ Cp, int ldc) {
    const int t    = threadIdx.x;
    const int wid  = t >> 6, lane = t & 63;
    const int gx  = gridDim.x;
    const int nwg = gx * gridDim.y;
    int lin = blockIdx.y * gx + blockIdx.x;
    lin = (lin & 7) * (nwg >> 3) + (lin >> 3);
    const int bx = lin % gx;
    const int nb = lin / gx;
    const int m0 = bx * 128;
    const int n0 = nb * 128;
    const int wr = wid >> 1, wc = wid & 1;
    __shared__ unsigned short Als[128 * 64];
    __shared__ unsigned short Bls[128 * 64];

    f32x4 acc[4][4];
    const f32x4 z4 = {0.f, 0.f, 0.f, 0.f};
#pragma unroll
    for (int m = 0; m < 4; ++m)
#pragma unroll
        for (int n = 0; n < 4; ++n) acc[m][n] = z4;

    int rowA[4], eoff[4];
#pragma unroll
    for (int i = 0; i < 4; ++i) {
        const int c = wid * 256 + i * 64 + lane;
        rowA[i] = c >> 3;
        eoff[i] = (c & 7) * 8;
    }
    const int ar = wr * 64 + (lane & 15);
    const int br = wc * 64 + (lane & 15);
    const int kq = (lane >> 4) * 8;

    for (int k0 = 0; k0 < K; k0 += 64) {
#pragma unroll
        for (int i = 0; i < 4; ++i) {
            const int dst = (wid * 4 + i) * 1024;
            gload16(A + (size_t)(m0 + rowA[i]) * K + k0 + eoff[i], (char*)Als + dst);
            gload16(B + (size_t)(n0 + rowA[i]) * K + k0 + eoff[i], (char*)Bls + dst);
        }
        __syncthreads();
        bf16x8 af[4][2], bfr[4][2];
#pragma unroll
        for (int m = 0; m < 4; ++m)
#pragma unroll
            for (int kk = 0; kk < 2; ++kk)
                af[m][kk] = *(const bf16x8*)&Als[(ar + m * 16) * 64 + kk * 32 + kq];
#pragma unroll
        for (int n = 0; n < 4; ++n)
#pragma unroll
            for (int kk = 0; kk < 2; ++kk)
                bfr[n][kk] = *(const bf16x8*)&Bls[(br + n * 16) * 64 + kk * 32 + kq];
#pragma unroll
        for (int m = 0; m < 4; ++m)
#pragma unroll
            for (int n = 0; n < 4; ++n)
#pragma unroll
                for (int kk = 0; kk < 2; ++kk)
                    acc[m][n] = __builtin_amdgcn_mfma_f32_16x16x32_bf16(
                        af[m][kk], bfr[n][kk], acc[m][n], 0, 0, 0);
        __syncthreads();
    }

    const int crow = (lane >> 4) * 4, ccol = lane & 15;
#pragma unroll
    for (int m = 0; m < 4; ++m)
#pragma unroll
        for (int n = 0; n < 4; ++n)
#pragma unroll
            for (int j = 0; j < 4; ++j) {
                const size_t idx = (size_t)(m0 + wr * 64 + m * 16 + crow + j) * ldc +
                                   (n0 + wc * 64 + n * 16 + ccol);
                if (BF16OUT) ((unsigned short*)Cp)[idx] = f2bf(acc[m][n][j]);
                else         ((float*)Cp)[idx] = acc[m][n][j];
            }
}

// ---------------------------------------------------------------------------
// k2: depthwise conv(k=3) + silu -> bf16 xsb, + fp32 row mean (xm).
// ---------------------------------------------------------------------------
__global__ __launch_bounds__(256) void k2_conv(const unsigned short* __restrict__ xz,
                                               const float* __restrict__ Wcv,
                                               unsigned short* __restrict__ xsb,
                                               float* __restrict__ xm) {
    const int t = threadIdx.x;
    const int wid = t >> 6, lane = t & 63;
    const int row0 = blockIdx.x * 16;
    const int c0 = t * 8;
    __shared__ float wsum[16][4];
    float w0[8], w1[8], w2[8];
#pragma unroll
    for (int j = 0; j < 8; ++j) {
        w0[j] = Wcv[(c0 + j) * 3 + 0];
        w1[j] = Wcv[(c0 + j) * 3 + 1];
        w2[j] = Wcv[(c0 + j) * 3 + 2];
    }
    for (int r = 0; r < 16; ++r) {
        const int row = row0 + r;
        const int l = row & (L_ - 1);
        const unsigned short* cur = xz + (size_t)row * NXZ_ + c0;
        float cv[8], pv[8] = {}, nv[8] = {};
        {
            const uint4 raw = *(const uint4*)cur;
            const unsigned short* p = (const unsigned short*)&raw;
#pragma unroll
            for (int j = 0; j < 8; ++j) cv[j] = bf2f(p[j]);
        }
        if (l > 0) {
            const uint4 raw = *(const uint4*)(cur - NXZ_);
            const unsigned short* p = (const unsigned short*)&raw;
#pragma unroll
            for (int j = 0; j < 8; ++j) pv[j] = bf2f(p[j]);
        }
        if (l < L_ - 1) {
            const uint4 raw = *(const uint4*)(cur + NXZ_);
            const unsigned short* p = (const unsigned short*)&raw;
#pragma unroll
            for (int j = 0; j < 8; ++j) nv[j] = bf2f(p[j]);
        }
        float s8 = 0.f;
        unsigned short o[8];
#pragma unroll
        for (int j = 0; j < 8; ++j) {
            const float v = cv[j] * w1[j] + pv[j] * w0[j] + nv[j] * w2[j];
            const float s = v / (1.f + expf(-v));
            o[j] = f2bf(s);
            s8 += s;
        }
        *(uint4*)(xsb + (size_t)row * DI_ + c0) = *(const uint4*)o;
#pragma unroll
        for (int k = 1; k < 64; k <<= 1) s8 += __shfl_xor(s8, k);
        if (lane == 0) wsum[r][wid] = s8;
    }
    __syncthreads();
    if (t < 16)
        xm[row0 + t] = (wsum[t][0] + wsum[t][1] + wsum[t][2] + wsum[t][3]) * (1.f / (float)DI_);
}

// ---------------------------------------------------------------------------
// k3m: split-K bf16 MFMA GEMM  xp_part[kc] = xsb @ WxpT^T (K-chunk 512).
// ---------------------------------------------------------------------------
__global__ __launch_bounds__(256, 2) void k3m(const unsigned short* __restrict__ A,
                                              const unsigned short* __restrict__ B,
                                              float* __restrict__ part) {
    const int t = threadIdx.x;
    const int wid = t >> 6, lane = t & 63;
    const int m0 = blockIdx.x * 128;
    const int kc = blockIdx.y;
    const int wr = wid >> 1, wc = wid & 1;
    __shared__ unsigned short Als[128 * 64];
    __shared__ unsigned short Bls[128 * 64];
    f32x4 acc[4][4];
    const f32x4 z4 = {0.f, 0.f, 0.f, 0.f};
#pragma unroll
    for (int m = 0; m < 4; ++m)
#pragma unroll
        for (int n = 0; n < 4; ++n) acc[m][n] = z4;
    int rowA[4], eoff[4];
#pragma unroll
    for (int i = 0; i < 4; ++i) {
        const int c = wid * 256 + i * 64 + lane;
        rowA[i] = c >> 3;
        eoff[i] = (c & 7) * 8;
    }
    const int ar = wr * 64 + (lane & 15);
    const int br = wc * 64 + (lane & 15);
    const int kq = (lane >> 4) * 8;
    const int kbase = kc * 512;
    for (int k0 = kbase; k0 < kbase + 512; k0 += 64) {
#pragma unroll
        for (int i = 0; i < 4; ++i) {
            const int dst = (wid * 4 + i) * 1024;
            gload16(A + (size_t)(m0 + rowA[i]) * DI_ + k0 + eoff[i], (char*)Als + dst);
            gload16(B + (size_t)rowA[i] * DI_ + k0 + eoff[i], (char*)Bls + dst);
        }
        __syncthreads();
        bf16x8 af[4][2], bfr[4][2];
#pragma unroll
        for (int m = 0; m < 4; ++m)
#pragma unroll
            for (int kk = 0; kk < 2; ++kk)
                af[m][kk] = *(const bf16x8*)&Als[(ar + m * 16) * 64 + kk * 32 + kq];
#pragma unroll
        for (int n = 0; n < 4; ++n)
#pragma unroll
            for (int kk = 0; kk < 2; ++kk)
                bfr[n][kk] = *(const bf16x8*)&Bls[(br + n * 16) * 64 + kk * 32 + kq];
#pragma unroll
        for (int m = 0; m < 4; ++m)
#pragma unroll
            for (int n = 0; n < 4; ++n)
#pragma unroll
                for (int kk = 0; kk < 2; ++kk)
                    acc[m][n] = __builtin_amdgcn_mfma_f32_16x16x32_bf16(
                        af[m][kk], bfr[n][kk], acc[m][n], 0, 0, 0);
        __syncthreads();
    }
    const int crow = (lane >> 4) * 4, ccol = lane & 15;
#pragma unroll
    for (int m = 0; m < 4; ++m)
#pragma unroll
        for (int n = 0; n < 4; ++n) {
            const int col = wc * 64 + n * 16 + ccol;
            if (col < 96) {
#pragma unroll
                for (int j = 0; j < 4; ++j)
                    part[((size_t)kc * ROWS_ + m0 + wr * 64 + m * 16 + crow + j) * 96 + col] =
                        acc[m][n][j];
            }
        }
}

// ---------------------------------------------------------------------------
// kred: xp = sum of 4 split-K partials; also emit dt_lo (cols 0..63) as bf16.
// ---------------------------------------------------------------------------
__global__ __launch_bounds__(256) void kred(const float* __restrict__ part,
                                            float* __restrict__ xp,
                                            unsigned short* __restrict__ dtlo) {
    const int i = blockIdx.x * 256 + threadIdx.x;
    const size_t stride = (size_t)ROWS_ * 96 / 4;
    const float4* p = (const float4*)part;
    float4 a = p[i], b = p[i + stride], c = p[i + 2 * stride], d = p[i + 3 * stride];
    float4 o;
    o.x = a.x + b.x + c.x + d.x;
    o.y = a.y + b.y + c.y + d.y;
    o.z = a.z + b.z + c.z + d.z;
    o.w = a.w + b.w + c.w + d.w;
    ((float4*)xp)[i] = o;
    const int c4 = i % 24, row = i / 24;
    if (c4 < 16) {
        ushort4 h;
        h.x = f2bf(o.x); h.y = f2bf(o.y); h.z = f2bf(o.z); h.w = f2bf(o.w);
        *(ushort4*)(dtlo + (size_t)row * 64 + c4 * 4) = h;
    }
}

// ---------------------------------------------------------------------------
// k4m: MFMA GEMM dt = dtlo @ WdtT^T (M=8192, N=2048, K=64) with fused
// softplus + per-128-col row sums -> psum[16][8192]. grid (64,16).
// ---------------------------------------------------------------------------
__global__ __launch_bounds__(256, 2) void k4m(const unsigned short* __restrict__ A,
                                              const unsigned short* __restrict__ B,
                                              const float* __restrict__ bdt,
                                              float* __restrict__ psum) {
    const int t = threadIdx.x;
    const int wid = t >> 6, lane = t & 63;
    const int m0 = blockIdx.x * 128;
    const int nb = blockIdx.y;
    const int wr = wid >> 1, wc = wid & 1;
    __shared__ unsigned short Als[128 * 64];
    __shared__ unsigned short Bls[128 * 64];
    __shared__ float srow[128][2];
    f32x4 acc[4][4];
    const f32x4 z4 = {0.f, 0.f, 0.f, 0.f};
#pragma unroll
    for (int m = 0; m < 4; ++m)
#pragma unroll
        for (int n = 0; n < 4; ++n) acc[m][n] = z4;
#pragma unroll
    for (int i = 0; i < 4; ++i) {
        const int c = wid * 256 + i * 64 + lane;
        const int row = c >> 3, eo = (c & 7) * 8;
        const int dst = (wid * 4 + i) * 1024;
        gload16(A + (size_t)(m0 + row) * 64 + eo, (char*)Als + dst);
        gload16(B + (size_t)(nb * 128 + row) * 64 + eo, (char*)Bls + dst);
    }
    __syncthreads();
    const int ar = wr * 64 + (lane & 15);
    const int br = wc * 64 + (lane & 15);
    const int kq = (lane >> 4) * 8;
    const int ccol = lane & 15;
    {
        bf16x8 af[4][2], bfr[4][2];
#pragma unroll
        for (int m = 0; m < 4; ++m)
#pragma unroll
            for (int kk = 0; kk < 2; ++kk)
                af[m][kk] = *(const bf16x8*)&Als[(ar + m * 16) * 64 + kk * 32 + kq];
#pragma unroll
        for (int n = 0; n < 4; ++n)
#pragma unroll
            for (int kk = 0; kk < 2; ++kk)
                bfr[n][kk] = *(const bf16x8*)&Bls[(br + n * 16) * 64 + kk * 32 + kq];
#pragma unroll
        for (int m = 0; m < 4; ++m)
#pragma unroll
            for (int n = 0; n < 4; ++n)
#pragma unroll
                for (int kk = 0; kk < 2; ++kk)
                    acc[m][n] = __builtin_amdgcn_mfma_f32_16x16x32_bf16(
                        af[m][kk], bfr[n][kk], acc[m][n], 0, 0, 0);
    }
    float bcol[4];
#pragma unroll
    for (int n = 0; n < 4; ++n) bcol[n] = bdt[nb * 128 + wc * 64 + n * 16 + ccol];
#pragma unroll
    for (int m = 0; m < 4; ++m)
#pragma unroll
        for (int j = 0; j < 4; ++j) {
            float s = 0.f;
#pragma unroll
            for (int n = 0; n < 4; ++n) {
                const float w = acc[m][n][j] + bcol[n];
                s += fmaxf(w, 0.f) + log1pf(expf(-fabsf(w)));   // softplus
            }
#pragma unroll
            for (int mask = 1; mask < 16; mask <<= 1) s += __shfl_xor(s, mask);
            if (ccol == 0)
                srow[wr * 64 + m * 16 + (lane >> 4) * 4 + j][wc] = s;
        }
    __syncthreads();
    if (t < 128)
        psum[(size_t)nb * ROWS_ + m0 + t] = srow[t][0] + srow[t][1];
}

// ---------------------------------------------------------------------------
// k4r: dtm = (sum of 16 psum)/2048; dec = exp(-dtm); u = xm * sum(Bp).
// ---------------------------------------------------------------------------
__global__ __launch_bounds__(256) void k4r(const float* __restrict__ psum,
                                           const float* __restrict__ xp,
                                           const float* __restrict__ xm,
                                           float* __restrict__ dec,
                                           float* __restrict__ u) {
    const int row = blockIdx.x * 256 + threadIdx.x;
    float tot = 0.f;
#pragma unroll
    for (int j = 0; j < 16; ++j) tot += psum[(size_t)j * ROWS_ + row];
    const float dtm = tot * (1.f / (float)DI_);
    float sBp = 0.f;
#pragma unroll
    for (int s = 0; s < DS_; ++s) sBp += xp[(size_t)row * 96 + DTR_ + s];
    dec[row] = expf(-dtm);
    u[row]   = xm[row] * sBp;
}

// ---------------------------------------------------------------------------
// k5: exact chunked scalar scan  S_l = d_l * S_{l-1} + u_l  (per batch).
// ---------------------------------------------------------------------------
__global__ __launch_bounds__(256) void k5_scan(const float* __restrict__ dec,
                                               const float* __restrict__ u,
                                               float* __restrict__ S) {
    const int t = threadIdx.x;
    __shared__ float aa[256], hh[256], init[256];
    const int b = t >> 7, c = t & 127;
    const int base = b * L_ + c * 32;
    float a = 1.f, h = 0.f;
    for (int i = 0; i < 32; ++i) {
        const float d = dec[base + i];
        h = h * d + u[base + i];
        a *= d;
    }
    aa[t] = a; hh[t] = h;
    __syncthreads();
    if (t < B_) {
        float run = 0.f;
        for (int cc = 0; cc < 128; ++cc) {
            const int tt = t * 128 + cc;
            init[tt] = run;
            run = hh[tt] + aa[tt] * run;
        }
    }
    __syncthreads();
    h = init[t];
    for (int i = 0; i < 32; ++i) {
        h = h * dec[base + i] + u[base + i];
        S[base + i] = h;
    }
}

// ---------------------------------------------------------------------------
// k6: per-row 16-vector v = Cp*S, LN stats over 16 (== LN over 2048 tile).
// ---------------------------------------------------------------------------
__global__ __launch_bounds__(256) void k6_v16(const float* __restrict__ xp,
                                              const float* __restrict__ S,
                                              float* __restrict__ v16) {
    const int row = blockIdx.x * 256 + threadIdx.x;
    const float s = S[row];
    float v[16], mu = 0.f;
#pragma unroll
    for (int i = 0; i < 16; ++i) {
        v[i] = xp[(size_t)row * 96 + DTR_ + DS_ + i] * s;
        mu += v[i];
    }
    mu *= (1.f / 16.f);
    float var = 0.f;
#pragma unroll
    for (int i = 0; i < 16; ++i) {
        const float d = v[i] - mu;
        var += d * d;
    }
    var *= (1.f / 16.f);
    const float rs = rsqrtf(var + 1e-5f);
#pragma unroll
    for (int i = 0; i < 16; ++i) v16[(size_t)row * 16 + i] = (v[i] - mu) * rs;
}

// ---------------------------------------------------------------------------
// kA7: Abf[row][i] = (v16[row][i&15]*g[i] + b[i]) * silu(z[row][i]), bf16.
// ---------------------------------------------------------------------------
__global__ __launch_bounds__(256) void kA7(const unsigned short* __restrict__ xz,
                                           const float* __restrict__ v16,
                                           const float* __restrict__ g,
                                           const float* __restrict__ bb,
                                           unsigned short* __restrict__ Abf) {
    const int row = blockIdx.x;
    const int t   = threadIdx.x;
    __shared__ float vrow[16];
    if (t < 16) vrow[t] = v16[row * 16 + t];
    __syncthreads();
    const int i0 = t * 8;
    const uint4 zraw = *(const uint4*)(xz + (size_t)row * NXZ_ + 2048 + i0);
    const unsigned short* zp = (const unsigned short*)&zraw;
    const float4 g0 = *(const float4*)(g + i0),  g1 = *(const float4*)(g + i0 + 4);
    const float4 b0 = *(const float4*)(bb + i0), b1 = *(const float4*)(bb + i0 + 4);
    const float gv[8] = {g0.x, g0.y, g0.z, g0.w, g1.x, g1.y, g1.z, g1.w};
    const float bv[8] = {b0.x, b0.y, b0.z, b0.w, b1.x, b1.y, b1.z, b1.w};
    unsigned short o[8];
#pragma unroll
    for (int j = 0; j < 8; ++j) {
        const int i = i0 + j;
        const float zf = bf2f(zp[j]);
        const float sz = zf / (1.f + expf(-zf));
        o[j] = f2bf((vrow[i & 15] * gv[j] + bv[j]) * sz);
    }
    *(uint4*)(Abf + (size_t)row * DI_ + i0) = *(const uint4*)o;
}

// ---------------------------------------------------------------------------
extern "C" void kernel_launch(void* const* d_in, const int* in_sizes, int n_in,
                              void* d_out, int out_size, void* d_ws, size_t ws_size,
                              hipStream_t stream) {
    const float* x    = (const float*)d_in[0];
    const float* Win  = (const float*)d_in[1];
    const float* Wcv  = (const float*)d_in[2];
    const float* Wxp  = (const float*)d_in[3];
    const float* Wdt  = (const float*)d_in[4];
    const float* bdt  = (const float*)d_in[5];
    const float* Wout = (const float*)d_in[6];
    const float* lng  = (const float*)d_in[7];
    const float* lnb  = (const float*)d_in[8];
    float* out = (float*)d_out;

    // ---- workspace layout (bytes), ~166 MB, lifetime-aliased ----
    char* base = (char*)d_ws;
    unsigned short* xz_bf   = (unsigned short*)(base + 0);           // 67.1 MB (k1->kA7)
    unsigned short* xsb     = (unsigned short*)(base + 67108864);    // 33.5 MB
    unsigned short* xbf     = (unsigned short*)(base + 100663296);   // 16.8 MB (dead after k1)
    unsigned short* Abf     = (unsigned short*)(base + 100663296);   // alias, 33.5 MB
    unsigned short* WoutT   = (unsigned short*)(base + 134217728);   // 4.2 MB
    unsigned short* WinT    = (unsigned short*)(base + 138412032);   // 8.4 MB
    unsigned short* WxpT    = (unsigned short*)(base + 146800640);   // 0.5 MB [128][2048]
    unsigned short* WdtT    = (unsigned short*)(base + 147324928);   // 0.26 MB [2048][64]
    float*          xp_part = (float*)(base + 147587072);            // 12.6 MB
    float*          xp      = (float*)(base + 160169984);            // 3.1 MB
    unsigned short* dtlo    = (unsigned short*)(base + 163315712);   // 1 MB [8192][64]
    float*          psum    = (float*)(base + 164364288);            // 0.5 MB [16][8192]
    float*          xm      = (float*)(base + 164888576);
    float*          dec     = (float*)(base + 164921344);
    float*          u       = (float*)(base + 164954112);
    float*          S       = (float*)(base + 164986880);
    float*          v16     = (float*)(base + 165019648);            // 0.5 MB

    kcvt<<<ROWS_ * D_ / 1024, 256, 0, stream>>>(x, xbf);
    ktrans<<<dim3(NXZ_ / 32, D_ / 32), 256, 0, stream>>>(Win, WinT, D_, NXZ_);
    ktrans<<<dim3(4, DI_ / 32), 256, 0, stream>>>(Wxp, WxpT, DI_, 96);
    ktrans<<<dim3(DI_ / 32, DTR_ / 32), 256, 0, stream>>>(Wdt, WdtT, DTR_, DI_);
    gemm256<D_><<<dim3(ROWS_ / 256, NXZ_ / 256), 512, 0, stream>>>(
        xbf, WinT, xz_bf, NXZ_);
    ktrans<<<dim3(D_ / 32, DI_ / 32), 256, 0, stream>>>(Wout, WoutT, DI_, D_);
    k2_conv<<<ROWS_ / 16, 256, 0, stream>>>(xz_bf, Wcv, xsb, xm);
    k3m<<<dim3(ROWS_ / 128, 4), 256, 0, stream>>>(xsb, WxpT, xp_part);
    kred<<<ROWS_ * 96 / 4 / 256, 256, 0, stream>>>(xp_part, xp, dtlo);
    k4m<<<dim3(ROWS_ / 128, DI_ / 128), 256, 0, stream>>>(dtlo, WdtT, bdt, psum);
    k4r<<<ROWS_ / 256, 256, 0, stream>>>(psum, xp, xm, dec, u);
    k5_scan<<<1, 256, 0, stream>>>(dec, u, S);
    k6_v16<<<ROWS_ / 256, 256, 0, stream>>>(xp, S, v16);
    kA7<<<ROWS_, 256, 0, stream>>>(xz_bf, v16, lng, lnb, Abf);
    gemm_bf16<DI_, false><<<dim3(ROWS_ / 128, D_ / 128), 256, 0, stream>>>(
        Abf, WoutT, out, D_);
}

// Round 7
// 394.631 us; speedup vs baseline: 1.8311x; 1.8311x over previous
//
#include <hip/hip_runtime.h>
#include <hip/hip_bf16.h>
#include <math.h>
#include <stdint.h>

#define D_    1024
#define DI_   2048
#define DS_   16
#define DTR_  64
#define B_    2
#define L_    4096
#define ROWS_ 8192
#define NXZ_  4096

typedef __attribute__((ext_vector_type(8))) __bf16 bf16x8;
typedef __attribute__((ext_vector_type(4))) float  f32x4;

__device__ __forceinline__ unsigned short f2bf(float f) {
    unsigned u = __float_as_uint(f);
    unsigned r = (u + 0x7fffu + ((u >> 16) & 1u)) >> 16;   // RNE
    return (unsigned short)r;
}
__device__ __forceinline__ float bf2f(unsigned short h) {
    return __uint_as_float(((unsigned)h) << 16);
}

// direct global->LDS 16B load (dest = wave-uniform base + lane*16)
__device__ __forceinline__ void gload16(const void* gp, void* lp) {
    auto* g1 = (const __attribute__((address_space(1))) unsigned int*)(uintptr_t)gp;
    auto* l3 = (__attribute__((address_space(3))) unsigned int*)(uintptr_t)lp;
    __builtin_amdgcn_global_load_lds(g1, l3, 16, 0, 0);
}

// ---------------------------------------------------------------------------
// cvt: fp32 -> bf16, same layout (for x)
// ---------------------------------------------------------------------------
__global__ __launch_bounds__(256) void kcvt(const float* __restrict__ in,
                                            unsigned short* __restrict__ out) {
    const int i = blockIdx.x * 256 + threadIdx.x;   // float4 index
    const float4 v = ((const float4*)in)[i];
    ushort4 o;
    o.x = f2bf(v.x); o.y = f2bf(v.y); o.z = f2bf(v.z); o.w = f2bf(v.w);
    ((ushort4*)out)[i] = o;
}

// ---------------------------------------------------------------------------
// transpose + cvt + col-pad: W [R][Csrc] f32 -> WT [gridDim.x*32][R] bf16
// ---------------------------------------------------------------------------
__global__ __launch_bounds__(256) void ktrans(const float* __restrict__ W,
                                              unsigned short* __restrict__ WT,
                                              int R, int Csrc) {
    __shared__ float tile[32][33];
    const int c0 = blockIdx.x * 32, r0 = blockIdx.y * 32;
    const int tc = threadIdx.x & 31, tr = threadIdx.x >> 5;   // tr: 0..7
#pragma unroll
    for (int i = 0; i < 32; i += 8)
        tile[tr + i][tc] = (c0 + tc < Csrc)
                           ? W[(size_t)(r0 + tr + i) * Csrc + c0 + tc] : 0.f;
    __syncthreads();
#pragma unroll
    for (int i = 0; i < 32; i += 8)
        WT[(size_t)(c0 + tr + i) * R + r0 + tc] = f2bf(tile[tc][tr + i]);
}

// ---------------------------------------------------------------------------
// gemm256b: 256x128 tile, BK=64, 8 waves (4M x 2N, 64x64 each), 8-phase
// schedule with counted vmcnt (T3+T4), chunk-XOR LDS swizzle (T2), setprio
// (T5), XCD swizzle (T1). A [M][K] bf16, B [N][K] bf16 (B^T of math matrix).
// Per-wave register shape matches the proven 128^2 kernel (acc=64 f32).
// LDS 96 KB: per-buf 48 KB = A(256x64) 32K + B(128x64) 16K, double-buffered.
// ---------------------------------------------------------------------------
template <int K, bool BF16OUT>
__global__ __launch_bounds__(512, 2) void gemm256b(const unsigned short* __restrict__ A,
                                                   const unsigned short* __restrict__ Bm,
                                                   void* __restrict__ Cp, int ldc) {
    constexpr int NT = K / 64;
    const int t = threadIdx.x;
    const int wid = t >> 6, lane = t & 63;
    const int l15 = lane & 15, g = lane >> 4;
    // T1: XCD-aware bijective swizzle (nwg % 8 == 0 for all our grids)
    const int gx = gridDim.x, nwg = gx * gridDim.y;
    int lin = blockIdx.y * gx + blockIdx.x;
    lin = (lin & 7) * (nwg >> 3) + (lin >> 3);
    const int m0 = (lin % gx) * 256;
    const int n0 = (lin / gx) * 128;
    const int wr = wid >> 1, wc = wid & 1;     // 4 M-bands x 2 N-bands

    __shared__ unsigned short lds[49152];      // 96 KB (2 bufs x 24576 shorts)

    // staging: unit = 128 rows x 64 cols = 1024 x 16B chunks = 2 instr/thread
    int pr[2], ps[2];
#pragma unroll
    for (int j = 0; j < 2; ++j) {
        const int p = (wid * 2 + j) * 64 + lane;   // chunk 0..1023
        pr[j] = p >> 3;                            // row in unit
        ps[j] = (p & 7) ^ (pr[j] & 7);             // T2 inverse-swizzled src slab
    }
    // which: 0 = A rows 0..127, 1 = A rows 128..255, 2 = B rows 0..127
    auto stage = [&](int kt, int which) {
        if (kt >= NT) return;
        const int buf = kt & 1;
        const unsigned short* src = (which == 2) ? Bm : A;
        const int row0 = (which == 2) ? n0 : (m0 + ((which == 1) ? 128 : 0));
        const int base_byte = buf * 49152 + which * 16384;
#pragma unroll
        for (int j = 0; j < 2; ++j)
            gload16(src + (size_t)(row0 + pr[j]) * K + kt * 64 + ps[j] * 8,
                    (char*)lds + base_byte + (wid * 2 + j) * 1024);
    };
    // swizzled ds_read of one bf16x8 fragment (16B)
    auto lda = [&](int buf, int m, int kk) -> bf16x8 {
        const int R = wr * 64 + m * 16 + l15;              // 0..255
        const int S = kk * 4 + g;
        return *(const bf16x8*)&lds[buf * 24576 + R * 64 + ((S ^ (l15 & 7)) << 3)];
    };
    auto ldb = [&](int buf, int n, int kk) -> bf16x8 {
        const int R = wc * 64 + n * 16 + l15;              // 0..127
        const int S = kk * 4 + g;
        return *(const bf16x8*)&lds[buf * 24576 + 16384 + R * 64 + ((S ^ (l15 & 7)) << 3)];
    };

    f32x4 acc[4][4];
    const f32x4 z4 = {0.f, 0.f, 0.f, 0.f};
#pragma unroll
    for (int m = 0; m < 4; ++m)
#pragma unroll
        for (int n = 0; n < 4; ++n) acc[m][n] = z4;
    bf16x8 a[2][2], b[4][2];

    // prologue: tile0 fully + A0(1); allow A0(1)'s 2 loads in flight
    stage(0, 0); stage(0, 1); stage(0, 2); stage(1, 0);
    asm volatile("s_waitcnt vmcnt(2)" ::: "memory");
    __builtin_amdgcn_s_barrier();

    for (int it = 0; it < NT; ++it) {
        const int buf = it & 1;
        // ---- phase 1: a(m0,m1) + b(n0,n1); stage A1(it+1) ----
#pragma unroll
        for (int m = 0; m < 2; ++m) { a[m][0] = lda(buf, m, 0); a[m][1] = lda(buf, m, 1); }
#pragma unroll
        for (int n = 0; n < 2; ++n) { b[n][0] = ldb(buf, n, 0); b[n][1] = ldb(buf, n, 1); }
        stage(it + 1, 1);
        __builtin_amdgcn_s_barrier();
        __builtin_amdgcn_s_setprio(1);
#pragma unroll
        for (int m = 0; m < 2; ++m)
#pragma unroll
            for (int n = 0; n < 2; ++n)
#pragma unroll
                for (int kk = 0; kk < 2; ++kk)
                    acc[m][n] = __builtin_amdgcn_mfma_f32_16x16x32_bf16(
                        a[m][kk], b[n][kk], acc[m][n], 0, 0, 0);
        __builtin_amdgcn_s_setprio(0);
        __builtin_amdgcn_s_barrier();
        // ---- phase 2: b(n2,n3); stage B(it+1) ----
#pragma unroll
        for (int n = 2; n < 4; ++n) { b[n][0] = ldb(buf, n, 0); b[n][1] = ldb(buf, n, 1); }
        stage(it + 1, 2);
        __builtin_amdgcn_s_barrier();
        __builtin_amdgcn_s_setprio(1);
#pragma unroll
        for (int m = 0; m < 2; ++m)
#pragma unroll
            for (int n = 2; n < 4; ++n)
#pragma unroll
                for (int kk = 0; kk < 2; ++kk)
                    acc[m][n] = __builtin_amdgcn_mfma_f32_16x16x32_bf16(
                        a[m][kk], b[n][kk], acc[m][n], 0, 0, 0);
        __builtin_amdgcn_s_setprio(0);
        __builtin_amdgcn_s_barrier();
        // ---- phase 3: a(m2,m3) ----
#pragma unroll
        for (int m = 0; m < 2; ++m) { a[m][0] = lda(buf, 2 + m, 0); a[m][1] = lda(buf, 2 + m, 1); }
        __builtin_amdgcn_s_barrier();
        __builtin_amdgcn_s_setprio(1);
#pragma unroll
        for (int m = 0; m < 2; ++m)
#pragma unroll
            for (int n = 0; n < 2; ++n)
#pragma unroll
                for (int kk = 0; kk < 2; ++kk)
                    acc[2 + m][n] = __builtin_amdgcn_mfma_f32_16x16x32_bf16(
                        a[m][kk], b[n][kk], acc[2 + m][n], 0, 0, 0);
        __builtin_amdgcn_s_setprio(0);
        __builtin_amdgcn_s_barrier();
        // ---- phase 4: stage A0(it+2) (A0 of this buf is done being read);
        //      counted vmcnt; next tile must be resident after this barrier ----
        stage(it + 2, 0);
        if (it < NT - 2)       { asm volatile("s_waitcnt vmcnt(2)" ::: "memory"); }
        else if (it == NT - 2) { asm volatile("s_waitcnt vmcnt(0)" ::: "memory"); }
        __builtin_amdgcn_s_barrier();
        __builtin_amdgcn_s_setprio(1);
#pragma unroll
        for (int m = 0; m < 2; ++m)
#pragma unroll
            for (int n = 2; n < 4; ++n)
#pragma unroll
                for (int kk = 0; kk < 2; ++kk)
                    acc[2 + m][n] = __builtin_amdgcn_mfma_f32_16x16x32_bf16(
                        a[m][kk], b[n][kk], acc[2 + m][n], 0, 0, 0);
        __builtin_amdgcn_s_setprio(0);
        __builtin_amdgcn_s_barrier();
    }

    const int crow = g * 4;
#pragma unroll
    for (int m = 0; m < 4; ++m)
#pragma unroll
        for (int n = 0; n < 4; ++n)
#pragma unroll
            for (int j = 0; j < 4; ++j) {
                const size_t idx = (size_t)(m0 + wr * 64 + m * 16 + crow + j) * ldc +
                                   (n0 + wc * 64 + n * 16 + l15);
                if (BF16OUT) ((unsigned short*)Cp)[idx] = f2bf(acc[m][n][j]);
                else         ((float*)Cp)[idx] = acc[m][n][j];
            }
}

// ---------------------------------------------------------------------------
// k2: depthwise conv(k=3) + silu -> bf16 xsb, + fp32 row mean (xm).
// ---------------------------------------------------------------------------
__global__ __launch_bounds__(256) void k2_conv(const unsigned short* __restrict__ xz,
                                               const float* __restrict__ Wcv,
                                               unsigned short* __restrict__ xsb,
                                               float* __restrict__ xm) {
    const int t = threadIdx.x;
    const int wid = t >> 6, lane = t & 63;
    const int row0 = blockIdx.x * 16;
    const int c0 = t * 8;
    __shared__ float wsum[16][4];
    float w0[8], w1[8], w2[8];
#pragma unroll
    for (int j = 0; j < 8; ++j) {
        w0[j] = Wcv[(c0 + j) * 3 + 0];
        w1[j] = Wcv[(c0 + j) * 3 + 1];
        w2[j] = Wcv[(c0 + j) * 3 + 2];
    }
    for (int r = 0; r < 16; ++r) {
        const int row = row0 + r;
        const int l = row & (L_ - 1);
        const unsigned short* cur = xz + (size_t)row * NXZ_ + c0;
        float cv[8], pv[8] = {}, nv[8] = {};
        {
            const uint4 raw = *(const uint4*)cur;
            const unsigned short* p = (const unsigned short*)&raw;
#pragma unroll
            for (int j = 0; j < 8; ++j) cv[j] = bf2f(p[j]);
        }
        if (l > 0) {
            const uint4 raw = *(const uint4*)(cur - NXZ_);
            const unsigned short* p = (const unsigned short*)&raw;
#pragma unroll
            for (int j = 0; j < 8; ++j) pv[j] = bf2f(p[j]);
        }
        if (l < L_ - 1) {
            const uint4 raw = *(const uint4*)(cur + NXZ_);
            const unsigned short* p = (const unsigned short*)&raw;
#pragma unroll
            for (int j = 0; j < 8; ++j) nv[j] = bf2f(p[j]);
        }
        float s8 = 0.f;
        unsigned short o[8];
#pragma unroll
        for (int j = 0; j < 8; ++j) {
            const float v = cv[j] * w1[j] + pv[j] * w0[j] + nv[j] * w2[j];
            const float s = v / (1.f + expf(-v));
            o[j] = f2bf(s);
            s8 += s;
        }
        *(uint4*)(xsb + (size_t)row * DI_ + c0) = *(const uint4*)o;
#pragma unroll
        for (int k = 1; k < 64; k <<= 1) s8 += __shfl_xor(s8, k);
        if (lane == 0) wsum[r][wid] = s8;
    }
    __syncthreads();
    if (t < 16)
        xm[row0 + t] = (wsum[t][0] + wsum[t][1] + wsum[t][2] + wsum[t][3]) * (1.f / (float)DI_);
}

// ---------------------------------------------------------------------------
// k3m: split-K bf16 MFMA GEMM  xp_part[kc] = xsb @ WxpT^T (K-chunk 512).
// ---------------------------------------------------------------------------
__global__ __launch_bounds__(256, 2) void k3m(const unsigned short* __restrict__ A,
                                              const unsigned short* __restrict__ B,
                                              float* __restrict__ part) {
    const int t = threadIdx.x;
    const int wid = t >> 6, lane = t & 63;
    const int m0 = blockIdx.x * 128;
    const int kc = blockIdx.y;
    const int wr = wid >> 1, wc = wid & 1;
    __shared__ unsigned short Als[128 * 64];
    __shared__ unsigned short Bls[128 * 64];
    f32x4 acc[4][4];
    const f32x4 z4 = {0.f, 0.f, 0.f, 0.f};
#pragma unroll
    for (int m = 0; m < 4; ++m)
#pragma unroll
        for (int n = 0; n < 4; ++n) acc[m][n] = z4;
    int rowA[4], eoff[4];
#pragma unroll
    for (int i = 0; i < 4; ++i) {
        const int c = wid * 256 + i * 64 + lane;
        rowA[i] = c >> 3;
        eoff[i] = (c & 7) * 8;
    }
    const int ar = wr * 64 + (lane & 15);
    const int br = wc * 64 + (lane & 15);
    const int kq = (lane >> 4) * 8;
    const int kbase = kc * 512;
    for (int k0 = kbase; k0 < kbase + 512; k0 += 64) {
#pragma unroll
        for (int i = 0; i < 4; ++i) {
            const int dst = (wid * 4 + i) * 1024;
            gload16(A + (size_t)(m0 + rowA[i]) * DI_ + k0 + eoff[i], (char*)Als + dst);
            gload16(B + (size_t)rowA[i] * DI_ + k0 + eoff[i], (char*)Bls + dst);
        }
        __syncthreads();
        bf16x8 af[4][2], bfr[4][2];
#pragma unroll
        for (int m = 0; m < 4; ++m)
#pragma unroll
            for (int kk = 0; kk < 2; ++kk)
                af[m][kk] = *(const bf16x8*)&Als[(ar + m * 16) * 64 + kk * 32 + kq];
#pragma unroll
        for (int n = 0; n < 4; ++n)
#pragma unroll
            for (int kk = 0; kk < 2; ++kk)
                bfr[n][kk] = *(const bf16x8*)&Bls[(br + n * 16) * 64 + kk * 32 + kq];
#pragma unroll
        for (int m = 0; m < 4; ++m)
#pragma unroll
            for (int n = 0; n < 4; ++n)
#pragma unroll
                for (int kk = 0; kk < 2; ++kk)
                    acc[m][n] = __builtin_amdgcn_mfma_f32_16x16x32_bf16(
                        af[m][kk], bfr[n][kk], acc[m][n], 0, 0, 0);
        __syncthreads();
    }
    const int crow = (lane >> 4) * 4, ccol = lane & 15;
#pragma unroll
    for (int m = 0; m < 4; ++m)
#pragma unroll
        for (int n = 0; n < 4; ++n) {
            const int col = wc * 64 + n * 16 + ccol;
            if (col < 96) {
#pragma unroll
                for (int j = 0; j < 4; ++j)
                    part[((size_t)kc * ROWS_ + m0 + wr * 64 + m * 16 + crow + j) * 96 + col] =
                        acc[m][n][j];
            }
        }
}

// ---------------------------------------------------------------------------
// kred: xp = sum of 4 split-K partials; also emit dt_lo (cols 0..63) as bf16.
// ---------------------------------------------------------------------------
__global__ __launch_bounds__(256) void kred(const float* __restrict__ part,
                                            float* __restrict__ xp,
                                            unsigned short* __restrict__ dtlo) {
    const int i = blockIdx.x * 256 + threadIdx.x;
    const size_t stride = (size_t)ROWS_ * 96 / 4;
    const float4* p = (const float4*)part;
    float4 a = p[i], b = p[i + stride], c = p[i + 2 * stride], d = p[i + 3 * stride];
    float4 o;
    o.x = a.x + b.x + c.x + d.x;
    o.y = a.y + b.y + c.y + d.y;
    o.z = a.z + b.z + c.z + d.z;
    o.w = a.w + b.w + c.w + d.w;
    ((float4*)xp)[i] = o;
    const int c4 = i % 24, row = i / 24;
    if (c4 < 16) {
        ushort4 h;
        h.x = f2bf(o.x); h.y = f2bf(o.y); h.z = f2bf(o.z); h.w = f2bf(o.w);
        *(ushort4*)(dtlo + (size_t)row * 64 + c4 * 4) = h;
    }
}

// ---------------------------------------------------------------------------
// k4m: MFMA GEMM dt = dtlo @ WdtT^T (M=8192, N=2048, K=64) with fused
// softplus + per-128-col row sums -> psum[16][8192]. grid (64,16).
// ---------------------------------------------------------------------------
__global__ __launch_bounds__(256, 2) void k4m(const unsigned short* __restrict__ A,
                                              const unsigned short* __restrict__ B,
                                              const float* __restrict__ bdt,
                                              float* __restrict__ psum) {
    const int t = threadIdx.x;
    const int wid = t >> 6, lane = t & 63;
    const int m0 = blockIdx.x * 128;
    const int nb = blockIdx.y;
    const int wr = wid >> 1, wc = wid & 1;
    __shared__ unsigned short Als[128 * 64];
    __shared__ unsigned short Bls[128 * 64];
    __shared__ float srow[128][2];
    f32x4 acc[4][4];
    const f32x4 z4 = {0.f, 0.f, 0.f, 0.f};
#pragma unroll
    for (int m = 0; m < 4; ++m)
#pragma unroll
        for (int n = 0; n < 4; ++n) acc[m][n] = z4;
#pragma unroll
    for (int i = 0; i < 4; ++i) {
        const int c = wid * 256 + i * 64 + lane;
        const int row = c >> 3, eo = (c & 7) * 8;
        const int dst = (wid * 4 + i) * 1024;
        gload16(A + (size_t)(m0 + row) * 64 + eo, (char*)Als + dst);
        gload16(B + (size_t)(nb * 128 + row) * 64 + eo, (char*)Bls + dst);
    }
    __syncthreads();
    const int ar = wr * 64 + (lane & 15);
    const int br = wc * 64 + (lane & 15);
    const int kq = (lane >> 4) * 8;
    const int ccol = lane & 15;
    {
        bf16x8 af[4][2], bfr[4][2];
#pragma unroll
        for (int m = 0; m < 4; ++m)
#pragma unroll
            for (int kk = 0; kk < 2; ++kk)
                af[m][kk] = *(const bf16x8*)&Als[(ar + m * 16) * 64 + kk * 32 + kq];
#pragma unroll
        for (int n = 0; n < 4; ++n)
#pragma unroll
            for (int kk = 0; kk < 2; ++kk)
                bfr[n][kk] = *(const bf16x8*)&Bls[(br + n * 16) * 64 + kk * 32 + kq];
#pragma unroll
        for (int m = 0; m < 4; ++m)
#pragma unroll
            for (int n = 0; n < 4; ++n)
#pragma unroll
                for (int kk = 0; kk < 2; ++kk)
                    acc[m][n] = __builtin_amdgcn_mfma_f32_16x16x32_bf16(
                        af[m][kk], bfr[n][kk], acc[m][n], 0, 0, 0);
    }
    float bcol[4];
#pragma unroll
    for (int n = 0; n < 4; ++n) bcol[n] = bdt[nb * 128 + wc * 64 + n * 16 + ccol];
#pragma unroll
    for (int m = 0; m < 4; ++m)
#pragma unroll
        for (int j = 0; j < 4; ++j) {
            float s = 0.f;
#pragma unroll
            for (int n = 0; n < 4; ++n) {
                const float w = acc[m][n][j] + bcol[n];
                s += fmaxf(w, 0.f) + log1pf(expf(-fabsf(w)));   // softplus
            }
#pragma unroll
            for (int mask = 1; mask < 16; mask <<= 1) s += __shfl_xor(s, mask);
            if (ccol == 0)
                srow[wr * 64 + m * 16 + (lane >> 4) * 4 + j][wc] = s;
        }
    __syncthreads();
    if (t < 128)
        psum[(size_t)nb * ROWS_ + m0 + t] = srow[t][0] + srow[t][1];
}

// ---------------------------------------------------------------------------
// k4r: dtm = (sum of 16 psum)/2048; dec = exp(-dtm); u = xm * sum(Bp).
// ---------------------------------------------------------------------------
__global__ __launch_bounds__(256) void k4r(const float* __restrict__ psum,
                                           const float* __restrict__ xp,
                                           const float* __restrict__ xm,
                                           float* __restrict__ dec,
                                           float* __restrict__ u) {
    const int row = blockIdx.x * 256 + threadIdx.x;
    float tot = 0.f;
#pragma unroll
    for (int j = 0; j < 16; ++j) tot += psum[(size_t)j * ROWS_ + row];
    const float dtm = tot * (1.f / (float)DI_);
    float sBp = 0.f;
#pragma unroll
    for (int s = 0; s < DS_; ++s) sBp += xp[(size_t)row * 96 + DTR_ + s];
    dec[row] = expf(-dtm);
    u[row]   = xm[row] * sBp;
}

// ---------------------------------------------------------------------------
// k5: exact chunked scalar scan  S_l = d_l * S_{l-1} + u_l  (per batch).
// ---------------------------------------------------------------------------
__global__ __launch_bounds__(256) void k5_scan(const float* __restrict__ dec,
                                               const float* __restrict__ u,
                                               float* __restrict__ S) {
    const int t = threadIdx.x;
    __shared__ float aa[256], hh[256], init[256];
    const int b = t >> 7, c = t & 127;
    const int base = b * L_ + c * 32;
    float a = 1.f, h = 0.f;
    for (int i = 0; i < 32; ++i) {
        const float d = dec[base + i];
        h = h * d + u[base + i];
        a *= d;
    }
    aa[t] = a; hh[t] = h;
    __syncthreads();
    if (t < B_) {
        float run = 0.f;
        for (int cc = 0; cc < 128; ++cc) {
            const int tt = t * 128 + cc;
            init[tt] = run;
            run = hh[tt] + aa[tt] * run;
        }
    }
    __syncthreads();
    h = init[t];
    for (int i = 0; i < 32; ++i) {
        h = h * dec[base + i] + u[base + i];
        S[base + i] = h;
    }
}

// ---------------------------------------------------------------------------
// k6: per-row 16-vector v = Cp*S, LN stats over 16 (== LN over 2048 tile).
// ---------------------------------------------------------------------------
__global__ __launch_bounds__(256) void k6_v16(const float* __restrict__ xp,
                                              const float* __restrict__ S,
                                              float* __restrict__ v16) {
    const int row = blockIdx.x * 256 + threadIdx.x;
    const float s = S[row];
    float v[16], mu = 0.f;
#pragma unroll
    for (int i = 0; i < 16; ++i) {
        v[i] = xp[(size_t)row * 96 + DTR_ + DS_ + i] * s;
        mu += v[i];
    }
    mu *= (1.f / 16.f);
    float var = 0.f;
#pragma unroll
    for (int i = 0; i < 16; ++i) {
        const float d = v[i] - mu;
        var += d * d;
    }
    var *= (1.f / 16.f);
    const float rs = rsqrtf(var + 1e-5f);
#pragma unroll
    for (int i = 0; i < 16; ++i) v16[(size_t)row * 16 + i] = (v[i] - mu) * rs;
}

// ---------------------------------------------------------------------------
// kA7: Abf[row][i] = (v16[row][i&15]*g[i] + b[i]) * silu(z[row][i]), bf16.
// ---------------------------------------------------------------------------
__global__ __launch_bounds__(256) void kA7(const unsigned short* __restrict__ xz,
                                           const float* __restrict__ v16,
                                           const float* __restrict__ g,
                                           const float* __restrict__ bb,
                                           unsigned short* __restrict__ Abf) {
    const int row = blockIdx.x;
    const int t   = threadIdx.x;
    __shared__ float vrow[16];
    if (t < 16) vrow[t] = v16[row * 16 + t];
    __syncthreads();
    const int i0 = t * 8;
    const uint4 zraw = *(const uint4*)(xz + (size_t)row * NXZ_ + 2048 + i0);
    const unsigned short* zp = (const unsigned short*)&zraw;
    const float4 g0 = *(const float4*)(g + i0),  g1 = *(const float4*)(g + i0 + 4);
    const float4 b0 = *(const float4*)(bb + i0), b1 = *(const float4*)(bb + i0 + 4);
    const float gv[8] = {g0.x, g0.y, g0.z, g0.w, g1.x, g1.y, g1.z, g1.w};
    const float bv[8] = {b0.x, b0.y, b0.z, b0.w, b1.x, b1.y, b1.z, b1.w};
    unsigned short o[8];
#pragma unroll
    for (int j = 0; j < 8; ++j) {
        const int i = i0 + j;
        const float zf = bf2f(zp[j]);
        const float sz = zf / (1.f + expf(-zf));
        o[j] = f2bf((vrow[i & 15] * gv[j] + bv[j]) * sz);
    }
    *(uint4*)(Abf + (size_t)row * DI_ + i0) = *(const uint4*)o;
}

// ---------------------------------------------------------------------------
extern "C" void kernel_launch(void* const* d_in, const int* in_sizes, int n_in,
                              void* d_out, int out_size, void* d_ws, size_t ws_size,
                              hipStream_t stream) {
    const float* x    = (const float*)d_in[0];
    const float* Win  = (const float*)d_in[1];
    const float* Wcv  = (const float*)d_in[2];
    const float* Wxp  = (const float*)d_in[3];
    const float* Wdt  = (const float*)d_in[4];
    const float* bdt  = (const float*)d_in[5];
    const float* Wout = (const float*)d_in[6];
    const float* lng  = (const float*)d_in[7];
    const float* lnb  = (const float*)d_in[8];
    float* out = (float*)d_out;

    // ---- workspace layout (bytes), ~166 MB, lifetime-aliased ----
    char* base = (char*)d_ws;
    unsigned short* xz_bf   = (unsigned short*)(base + 0);           // 67.1 MB (k1->kA7)
    unsigned short* xsb     = (unsigned short*)(base + 67108864);    // 33.5 MB
    unsigned short* xbf     = (unsigned short*)(base + 100663296);   // 16.8 MB (dead after k1)
    unsigned short* Abf     = (unsigned short*)(base + 100663296);   // alias, 33.5 MB
    unsigned short* WoutT   = (unsigned short*)(base + 134217728);   // 4.2 MB
    unsigned short* WinT    = (unsigned short*)(base + 138412032);   // 8.4 MB
    unsigned short* WxpT    = (unsigned short*)(base + 146800640);   // 0.5 MB [128][2048]
    unsigned short* WdtT    = (unsigned short*)(base + 147324928);   // 0.26 MB [2048][64]
    float*          xp_part = (float*)(base + 147587072);            // 12.6 MB
    float*          xp      = (float*)(base + 160169984);            // 3.1 MB
    unsigned short* dtlo    = (unsigned short*)(base + 163315712);   // 1 MB [8192][64]
    float*          psum    = (float*)(base + 164364288);            // 0.5 MB [16][8192]
    float*          xm      = (float*)(base + 164888576);
    float*          dec     = (float*)(base + 164921344);
    float*          u       = (float*)(base + 164954112);
    float*          S       = (float*)(base + 164986880);
    float*          v16     = (float*)(base + 165019648);            // 0.5 MB

    kcvt<<<ROWS_ * D_ / 1024, 256, 0, stream>>>(x, xbf);
    ktrans<<<dim3(NXZ_ / 32, D_ / 32), 256, 0, stream>>>(Win, WinT, D_, NXZ_);
    ktrans<<<dim3(4, DI_ / 32), 256, 0, stream>>>(Wxp, WxpT, DI_, 96);
    ktrans<<<dim3(DI_ / 32, DTR_ / 32), 256, 0, stream>>>(Wdt, WdtT, DTR_, DI_);
    gemm256b<D_, true><<<dim3(ROWS_ / 256, NXZ_ / 128), 512, 0, stream>>>(
        xbf, WinT, xz_bf, NXZ_);
    ktrans<<<dim3(D_ / 32, DI_ / 32), 256, 0, stream>>>(Wout, WoutT, DI_, D_);
    k2_conv<<<ROWS_ / 16, 256, 0, stream>>>(xz_bf, Wcv, xsb, xm);
    k3m<<<dim3(ROWS_ / 128, 4), 256, 0, stream>>>(xsb, WxpT, xp_part);
    kred<<<ROWS_ * 96 / 4 / 256, 256, 0, stream>>>(xp_part, xp, dtlo);
    k4m<<<dim3(ROWS_ / 128, DI_ / 128), 256, 0, stream>>>(dtlo, WdtT, bdt, psum);
    k4r<<<ROWS_ / 256, 256, 0, stream>>>(psum, xp, xm, dec, u);
    k5_scan<<<1, 256, 0, stream>>>(dec, u, S);
    k6_v16<<<ROWS_ / 256, 256, 0, stream>>>(xp, S, v16);
    kA7<<<ROWS_, 256, 0, stream>>>(xz_bf, v16, lng, lnb, Abf);
    gemm256b<DI_, false><<<dim3(ROWS_ / 256, D_ / 128), 512, 0, stream>>>(
        Abf, WoutT, out, D_);
}

// Round 8
// 391.178 us; speedup vs baseline: 1.8472x; 1.0088x over previous
//
#include <hip/hip_runtime.h>
#include <hip/hip_bf16.h>
#include <math.h>
#include <stdint.h>

#define D_    1024
#define DI_   2048
#define DS_   16
#define DTR_  64
#define B_    2
#define L_    4096
#define ROWS_ 8192
#define NXZ_  4096

typedef __attribute__((ext_vector_type(8))) __bf16 bf16x8;
typedef __attribute__((ext_vector_type(4))) float  f32x4;

__device__ __forceinline__ unsigned short f2bf(float f) {
    unsigned u = __float_as_uint(f);
    unsigned r = (u + 0x7fffu + ((u >> 16) & 1u)) >> 16;   // RNE
    return (unsigned short)r;
}
__device__ __forceinline__ float bf2f(unsigned short h) {
    return __uint_as_float(((unsigned)h) << 16);
}

// direct global->LDS 16B load (dest = wave-uniform base + lane*16)
__device__ __forceinline__ void gload16(const void* gp, void* lp) {
    auto* g1 = (const __attribute__((address_space(1))) unsigned int*)(uintptr_t)gp;
    auto* l3 = (__attribute__((address_space(3))) unsigned int*)(uintptr_t)lp;
    __builtin_amdgcn_global_load_lds(g1, l3, 16, 0, 0);
}

// ---------------------------------------------------------------------------
// cvt: fp32 -> bf16, same layout (for x)
// ---------------------------------------------------------------------------
__global__ __launch_bounds__(256) void kcvt(const float* __restrict__ in,
                                            unsigned short* __restrict__ out) {
    const int i = blockIdx.x * 256 + threadIdx.x;   // float4 index
    const float4 v = ((const float4*)in)[i];
    ushort4 o;
    o.x = f2bf(v.x); o.y = f2bf(v.y); o.z = f2bf(v.z); o.w = f2bf(v.w);
    ((ushort4*)out)[i] = o;
}

// ---------------------------------------------------------------------------
// transpose + cvt + col-pad: W [R][Csrc] f32 -> WT [gridDim.x*32][R] bf16
// ---------------------------------------------------------------------------
__global__ __launch_bounds__(256) void ktrans(const float* __restrict__ W,
                                              unsigned short* __restrict__ WT,
                                              int R, int Csrc) {
    __shared__ float tile[32][33];
    const int c0 = blockIdx.x * 32, r0 = blockIdx.y * 32;
    const int tc = threadIdx.x & 31, tr = threadIdx.x >> 5;   // tr: 0..7
#pragma unroll
    for (int i = 0; i < 32; i += 8)
        tile[tr + i][tc] = (c0 + tc < Csrc)
                           ? W[(size_t)(r0 + tr + i) * Csrc + c0 + tc] : 0.f;
    __syncthreads();
#pragma unroll
    for (int i = 0; i < 32; i += 8)
        WT[(size_t)(c0 + tr + i) * R + r0 + tc] = f2bf(tile[tc][tr + i]);
}

// ---------------------------------------------------------------------------
// gemm256b: 256x128 tile, BK=64, 8 waves (4M x 2N, 64x64 each).
// 2 phases per K-tile (16-MFMA clusters), TRIPLE-buffered LDS (3 x 48 KB),
// counted vmcnt(6) (T3+T4), chunk-XOR swizzle (T2), setprio (T5), XCD
// swizzle (T1). A [M][K] bf16, B [N][K] bf16 (B^T of math matrix).
// ---------------------------------------------------------------------------
template <int K, bool BF16OUT>
__global__ __launch_bounds__(512, 2) void gemm256b(const unsigned short* __restrict__ A,
                                                   const unsigned short* __restrict__ Bm,
                                                   void* __restrict__ Cp, int ldc) {
    constexpr int NT = K / 64;
    const int t = threadIdx.x;
    const int wid = t >> 6, lane = t & 63;
    const int l15 = lane & 15, g = lane >> 4;
    // T1: XCD-aware bijective swizzle (nwg % 8 == 0 for all our grids)
    const int gx = gridDim.x, nwg = gx * gridDim.y;
    int lin = blockIdx.y * gx + blockIdx.x;
    lin = (lin & 7) * (nwg >> 3) + (lin >> 3);
    const int m0 = (lin % gx) * 256;
    const int n0 = (lin / gx) * 128;
    const int wr = wid >> 1, wc = wid & 1;     // 4 M-bands x 2 N-bands

    __shared__ unsigned short lds[73728];      // 144 KB = 3 bufs x 24576 shorts

    // staging: unit = 128 rows x 64 cols = 1024 x 16B chunks = 2 instr/thread
    int pr[2], ps[2];
#pragma unroll
    for (int j = 0; j < 2; ++j) {
        const int p = (wid * 2 + j) * 64 + lane;   // chunk 0..1023
        pr[j] = p >> 3;                            // row in unit
        ps[j] = (p & 7) ^ (pr[j] & 7);             // T2 inverse-swizzled src slab
    }
    // which: 0 = A rows 0..127, 1 = A rows 128..255, 2 = B rows 0..127
    auto stage = [&](int kt, int which) {
        if (kt >= NT) return;
        const int buf = kt % 3;
        const unsigned short* src = (which == 2) ? Bm : A;
        const int row0 = (which == 2) ? n0 : (m0 + ((which == 1) ? 128 : 0));
        const int base_byte = buf * 49152 + which * 16384;
#pragma unroll
        for (int j = 0; j < 2; ++j)
            gload16(src + (size_t)(row0 + pr[j]) * K + kt * 64 + ps[j] * 8,
                    (char*)lds + base_byte + (wid * 2 + j) * 1024);
    };
    // swizzled ds_read of one bf16x8 fragment (16B)
    auto lda = [&](int buf, int m, int kk) -> bf16x8 {
        const int R = wr * 64 + m * 16 + l15;              // 0..255
        const int S = kk * 4 + g;
        return *(const bf16x8*)&lds[buf * 24576 + R * 64 + ((S ^ (l15 & 7)) << 3)];
    };
    auto ldb = [&](int buf, int n, int kk) -> bf16x8 {
        const int R = wc * 64 + n * 16 + l15;              // 0..127
        const int S = kk * 4 + g;
        return *(const bf16x8*)&lds[buf * 24576 + 16384 + R * 64 + ((S ^ (l15 & 7)) << 3)];
    };

    f32x4 acc[4][4];
    const f32x4 z4 = {0.f, 0.f, 0.f, 0.f};
#pragma unroll
    for (int m = 0; m < 4; ++m)
#pragma unroll
        for (int n = 0; n < 4; ++n) acc[m][n] = z4;
    bf16x8 a[2][2], b[4][2];

    // prologue: tiles 0 and 1 fully staged; wait tile 0 (6 of tile 1 in flight)
    stage(0, 0); stage(0, 1); stage(0, 2);
    stage(1, 0); stage(1, 1); stage(1, 2);
    asm volatile("s_waitcnt vmcnt(6)" ::: "memory");
    __builtin_amdgcn_s_barrier();

    for (int it = 0; it < NT; ++it) {
        const int buf = it % 3;
        // ---- phase 1: a(m0,m1) + b(all 4 n); stage A1(it+2), B(it+2) ----
#pragma unroll
        for (int m = 0; m < 2; ++m) { a[m][0] = lda(buf, m, 0); a[m][1] = lda(buf, m, 1); }
#pragma unroll
        for (int n = 0; n < 4; ++n) { b[n][0] = ldb(buf, n, 0); b[n][1] = ldb(buf, n, 1); }
        stage(it + 2, 1);
        stage(it + 2, 2);
        __builtin_amdgcn_s_barrier();
        __builtin_amdgcn_s_setprio(1);
#pragma unroll
        for (int m = 0; m < 2; ++m)
#pragma unroll
            for (int n = 0; n < 4; ++n)
#pragma unroll
                for (int kk = 0; kk < 2; ++kk)
                    acc[m][n] = __builtin_amdgcn_mfma_f32_16x16x32_bf16(
                        a[m][kk], b[n][kk], acc[m][n], 0, 0, 0);
        __builtin_amdgcn_s_setprio(0);
        __builtin_amdgcn_s_barrier();
        // ---- phase 2: a(m2,m3); stage A0(it+2); counted vmcnt ----
#pragma unroll
        for (int m = 0; m < 2; ++m) { a[m][0] = lda(buf, 2 + m, 0); a[m][1] = lda(buf, 2 + m, 1); }
        stage(it + 2, 0);
        if (it < NT - 2)       { asm volatile("s_waitcnt vmcnt(6)" ::: "memory"); }
        else if (it == NT - 2) { asm volatile("s_waitcnt vmcnt(0)" ::: "memory"); }
        __builtin_amdgcn_s_barrier();
        __builtin_amdgcn_s_setprio(1);
#pragma unroll
        for (int m = 0; m < 2; ++m)
#pragma unroll
            for (int n = 0; n < 4; ++n)
#pragma unroll
                for (int kk = 0; kk < 2; ++kk)
                    acc[2 + m][n] = __builtin_amdgcn_mfma_f32_16x16x32_bf16(
                        a[m][kk], b[n][kk], acc[2 + m][n], 0, 0, 0);
        __builtin_amdgcn_s_setprio(0);
        __builtin_amdgcn_s_barrier();
    }

    const int crow = g * 4;
#pragma unroll
    for (int m = 0; m < 4; ++m)
#pragma unroll
        for (int n = 0; n < 4; ++n)
#pragma unroll
            for (int j = 0; j < 4; ++j) {
                const size_t idx = (size_t)(m0 + wr * 64 + m * 16 + crow + j) * ldc +
                                   (n0 + wc * 64 + n * 16 + l15);
                if (BF16OUT) ((unsigned short*)Cp)[idx] = f2bf(acc[m][n][j]);
                else         ((float*)Cp)[idx] = acc[m][n][j];
            }
}

// ---------------------------------------------------------------------------
// k2: depthwise conv(k=3) + silu -> bf16 xsb, + fp32 row mean (xm).
// ---------------------------------------------------------------------------
__global__ __launch_bounds__(256) void k2_conv(const unsigned short* __restrict__ xz,
                                               const float* __restrict__ Wcv,
                                               unsigned short* __restrict__ xsb,
                                               float* __restrict__ xm) {
    const int t = threadIdx.x;
    const int wid = t >> 6, lane = t & 63;
    const int row0 = blockIdx.x * 16;
    const int c0 = t * 8;
    __shared__ float wsum[16][4];
    float w0[8], w1[8], w2[8];
#pragma unroll
    for (int j = 0; j < 8; ++j) {
        w0[j] = Wcv[(c0 + j) * 3 + 0];
        w1[j] = Wcv[(c0 + j) * 3 + 1];
        w2[j] = Wcv[(c0 + j) * 3 + 2];
    }
    for (int r = 0; r < 16; ++r) {
        const int row = row0 + r;
        const int l = row & (L_ - 1);
        const unsigned short* cur = xz + (size_t)row * NXZ_ + c0;
        float cv[8], pv[8] = {}, nv[8] = {};
        {
            const uint4 raw = *(const uint4*)cur;
            const unsigned short* p = (const unsigned short*)&raw;
#pragma unroll
            for (int j = 0; j < 8; ++j) cv[j] = bf2f(p[j]);
        }
        if (l > 0) {
            const uint4 raw = *(const uint4*)(cur - NXZ_);
            const unsigned short* p = (const unsigned short*)&raw;
#pragma unroll
            for (int j = 0; j < 8; ++j) pv[j] = bf2f(p[j]);
        }
        if (l < L_ - 1) {
            const uint4 raw = *(const uint4*)(cur + NXZ_);
            const unsigned short* p = (const unsigned short*)&raw;
#pragma unroll
            for (int j = 0; j < 8; ++j) nv[j] = bf2f(p[j]);
        }
        float s8 = 0.f;
        unsigned short o[8];
#pragma unroll
        for (int j = 0; j < 8; ++j) {
            const float v = cv[j] * w1[j] + pv[j] * w0[j] + nv[j] * w2[j];
            const float s = v / (1.f + expf(-v));
            o[j] = f2bf(s);
            s8 += s;
        }
        *(uint4*)(xsb + (size_t)row * DI_ + c0) = *(const uint4*)o;
#pragma unroll
        for (int k = 1; k < 64; k <<= 1) s8 += __shfl_xor(s8, k);
        if (lane == 0) wsum[r][wid] = s8;
    }
    __syncthreads();
    if (t < 16)
        xm[row0 + t] = (wsum[t][0] + wsum[t][1] + wsum[t][2] + wsum[t][3]) * (1.f / (float)DI_);
}

// ---------------------------------------------------------------------------
// k3m: split-K bf16 MFMA GEMM  xp_part[kc] = xsb @ WxpT^T (K-chunk 512).
// ---------------------------------------------------------------------------
__global__ __launch_bounds__(256, 2) void k3m(const unsigned short* __restrict__ A,
                                              const unsigned short* __restrict__ B,
                                              float* __restrict__ part) {
    const int t = threadIdx.x;
    const int wid = t >> 6, lane = t & 63;
    const int m0 = blockIdx.x * 128;
    const int kc = blockIdx.y;
    const int wr = wid >> 1, wc = wid & 1;
    __shared__ unsigned short Als[128 * 64];
    __shared__ unsigned short Bls[128 * 64];
    f32x4 acc[4][4];
    const f32x4 z4 = {0.f, 0.f, 0.f, 0.f};
#pragma unroll
    for (int m = 0; m < 4; ++m)
#pragma unroll
        for (int n = 0; n < 4; ++n) acc[m][n] = z4;
    int rowA[4], eoff[4];
#pragma unroll
    for (int i = 0; i < 4; ++i) {
        const int c = wid * 256 + i * 64 + lane;
        rowA[i] = c >> 3;
        eoff[i] = (c & 7) * 8;
    }
    const int ar = wr * 64 + (lane & 15);
    const int br = wc * 64 + (lane & 15);
    const int kq = (lane >> 4) * 8;
    const int kbase = kc * 512;
    for (int k0 = kbase; k0 < kbase + 512; k0 += 64) {
#pragma unroll
        for (int i = 0; i < 4; ++i) {
            const int dst = (wid * 4 + i) * 1024;
            gload16(A + (size_t)(m0 + rowA[i]) * DI_ + k0 + eoff[i], (char*)Als + dst);
            gload16(B + (size_t)rowA[i] * DI_ + k0 + eoff[i], (char*)Bls + dst);
        }
        __syncthreads();
        bf16x8 af[4][2], bfr[4][2];
#pragma unroll
        for (int m = 0; m < 4; ++m)
#pragma unroll
            for (int kk = 0; kk < 2; ++kk)
                af[m][kk] = *(const bf16x8*)&Als[(ar + m * 16) * 64 + kk * 32 + kq];
#pragma unroll
        for (int n = 0; n < 4; ++n)
#pragma unroll
            for (int kk = 0; kk < 2; ++kk)
                bfr[n][kk] = *(const bf16x8*)&Bls[(br + n * 16) * 64 + kk * 32 + kq];
#pragma unroll
        for (int m = 0; m < 4; ++m)
#pragma unroll
            for (int n = 0; n < 4; ++n)
#pragma unroll
                for (int kk = 0; kk < 2; ++kk)
                    acc[m][n] = __builtin_amdgcn_mfma_f32_16x16x32_bf16(
                        af[m][kk], bfr[n][kk], acc[m][n], 0, 0, 0);
        __syncthreads();
    }
    const int crow = (lane >> 4) * 4, ccol = lane & 15;
#pragma unroll
    for (int m = 0; m < 4; ++m)
#pragma unroll
        for (int n = 0; n < 4; ++n) {
            const int col = wc * 64 + n * 16 + ccol;
            if (col < 96) {
#pragma unroll
                for (int j = 0; j < 4; ++j)
                    part[((size_t)kc * ROWS_ + m0 + wr * 64 + m * 16 + crow + j) * 96 + col] =
                        acc[m][n][j];
            }
        }
}

// ---------------------------------------------------------------------------
// kred: xp = sum of 4 split-K partials; also emit dt_lo (cols 0..63) as bf16.
// ---------------------------------------------------------------------------
__global__ __launch_bounds__(256) void kred(const float* __restrict__ part,
                                            float* __restrict__ xp,
                                            unsigned short* __restrict__ dtlo) {
    const int i = blockIdx.x * 256 + threadIdx.x;
    const size_t stride = (size_t)ROWS_ * 96 / 4;
    const float4* p = (const float4*)part;
    float4 a = p[i], b = p[i + stride], c = p[i + 2 * stride], d = p[i + 3 * stride];
    float4 o;
    o.x = a.x + b.x + c.x + d.x;
    o.y = a.y + b.y + c.y + d.y;
    o.z = a.z + b.z + c.z + d.z;
    o.w = a.w + b.w + c.w + d.w;
    ((float4*)xp)[i] = o;
    const int c4 = i % 24, row = i / 24;
    if (c4 < 16) {
        ushort4 h;
        h.x = f2bf(o.x); h.y = f2bf(o.y); h.z = f2bf(o.z); h.w = f2bf(o.w);
        *(ushort4*)(dtlo + (size_t)row * 64 + c4 * 4) = h;
    }
}

// ---------------------------------------------------------------------------
// k4m: MFMA GEMM dt = dtlo @ WdtT^T (M=8192, N=2048, K=64) with fused
// softplus + per-128-col row sums -> psum[16][8192]. grid (64,16).
// ---------------------------------------------------------------------------
__global__ __launch_bounds__(256, 2) void k4m(const unsigned short* __restrict__ A,
                                              const unsigned short* __restrict__ B,
                                              const float* __restrict__ bdt,
                                              float* __restrict__ psum) {
    const int t = threadIdx.x;
    const int wid = t >> 6, lane = t & 63;
    const int m0 = blockIdx.x * 128;
    const int nb = blockIdx.y;
    const int wr = wid >> 1, wc = wid & 1;
    __shared__ unsigned short Als[128 * 64];
    __shared__ unsigned short Bls[128 * 64];
    __shared__ float srow[128][2];
    f32x4 acc[4][4];
    const f32x4 z4 = {0.f, 0.f, 0.f, 0.f};
#pragma unroll
    for (int m = 0; m < 4; ++m)
#pragma unroll
        for (int n = 0; n < 4; ++n) acc[m][n] = z4;
#pragma unroll
    for (int i = 0; i < 4; ++i) {
        const int c = wid * 256 + i * 64 + lane;
        const int row = c >> 3, eo = (c & 7) * 8;
        const int dst = (wid * 4 + i) * 1024;
        gload16(A + (size_t)(m0 + row) * 64 + eo, (char*)Als + dst);
        gload16(B + (size_t)(nb * 128 + row) * 64 + eo, (char*)Bls + dst);
    }
    __syncthreads();
    const int ar = wr * 64 + (lane & 15);
    const int br = wc * 64 + (lane & 15);
    const int kq = (lane >> 4) * 8;
    const int ccol = lane & 15;
    {
        bf16x8 af[4][2], bfr[4][2];
#pragma unroll
        for (int m = 0; m < 4; ++m)
#pragma unroll
            for (int kk = 0; kk < 2; ++kk)
                af[m][kk] = *(const bf16x8*)&Als[(ar + m * 16) * 64 + kk * 32 + kq];
#pragma unroll
        for (int n = 0; n < 4; ++n)
#pragma unroll
            for (int kk = 0; kk < 2; ++kk)
                bfr[n][kk] = *(const bf16x8*)&Bls[(br + n * 16) * 64 + kk * 32 + kq];
#pragma unroll
        for (int m = 0; m < 4; ++m)
#pragma unroll
            for (int n = 0; n < 4; ++n)
#pragma unroll
                for (int kk = 0; kk < 2; ++kk)
                    acc[m][n] = __builtin_amdgcn_mfma_f32_16x16x32_bf16(
                        af[m][kk], bfr[n][kk], acc[m][n], 0, 0, 0);
    }
    float bcol[4];
#pragma unroll
    for (int n = 0; n < 4; ++n) bcol[n] = bdt[nb * 128 + wc * 64 + n * 16 + ccol];
#pragma unroll
    for (int m = 0; m < 4; ++m)
#pragma unroll
        for (int j = 0; j < 4; ++j) {
            float s = 0.f;
#pragma unroll
            for (int n = 0; n < 4; ++n) {
                const float w = acc[m][n][j] + bcol[n];
                s += fmaxf(w, 0.f) + log1pf(expf(-fabsf(w)));   // softplus
            }
#pragma unroll
            for (int mask = 1; mask < 16; mask <<= 1) s += __shfl_xor(s, mask);
            if (ccol == 0)
                srow[wr * 64 + m * 16 + (lane >> 4) * 4 + j][wc] = s;
        }
    __syncthreads();
    if (t < 128)
        psum[(size_t)nb * ROWS_ + m0 + t] = srow[t][0] + srow[t][1];
}

// ---------------------------------------------------------------------------
// k4r: dtm = (sum of 16 psum)/2048; dec = exp(-dtm); u = xm * sum(Bp).
// ---------------------------------------------------------------------------
__global__ __launch_bounds__(256) void k4r(const float* __restrict__ psum,
                                           const float* __restrict__ xp,
                                           const float* __restrict__ xm,
                                           float* __restrict__ dec,
                                           float* __restrict__ u) {
    const int row = blockIdx.x * 256 + threadIdx.x;
    float tot = 0.f;
#pragma unroll
    for (int j = 0; j < 16; ++j) tot += psum[(size_t)j * ROWS_ + row];
    const float dtm = tot * (1.f / (float)DI_);
    float sBp = 0.f;
#pragma unroll
    for (int s = 0; s < DS_; ++s) sBp += xp[(size_t)row * 96 + DTR_ + s];
    dec[row] = expf(-dtm);
    u[row]   = xm[row] * sBp;
}

// ---------------------------------------------------------------------------
// k5: exact chunked scalar scan  S_l = d_l * S_{l-1} + u_l  (per batch).
// ---------------------------------------------------------------------------
__global__ __launch_bounds__(256) void k5_scan(const float* __restrict__ dec,
                                               const float* __restrict__ u,
                                               float* __restrict__ S) {
    const int t = threadIdx.x;
    __shared__ float aa[256], hh[256], init[256];
    const int b = t >> 7, c = t & 127;
    const int base = b * L_ + c * 32;
    float a = 1.f, h = 0.f;
    for (int i = 0; i < 32; ++i) {
        const float d = dec[base + i];
        h = h * d + u[base + i];
        a *= d;
    }
    aa[t] = a; hh[t] = h;
    __syncthreads();
    if (t < B_) {
        float run = 0.f;
        for (int cc = 0; cc < 128; ++cc) {
            const int tt = t * 128 + cc;
            init[tt] = run;
            run = hh[tt] + aa[tt] * run;
        }
    }
    __syncthreads();
    h = init[t];
    for (int i = 0; i < 32; ++i) {
        h = h * dec[base + i] + u[base + i];
        S[base + i] = h;
    }
}

// ---------------------------------------------------------------------------
// k6: per-row 16-vector v = Cp*S, LN stats over 16 (== LN over 2048 tile).
// ---------------------------------------------------------------------------
__global__ __launch_bounds__(256) void k6_v16(const float* __restrict__ xp,
                                              const float* __restrict__ S,
                                              float* __restrict__ v16) {
    const int row = blockIdx.x * 256 + threadIdx.x;
    const float s = S[row];
    float v[16], mu = 0.f;
#pragma unroll
    for (int i = 0; i < 16; ++i) {
        v[i] = xp[(size_t)row * 96 + DTR_ + DS_ + i] * s;
        mu += v[i];
    }
    mu *= (1.f / 16.f);
    float var = 0.f;
#pragma unroll
    for (int i = 0; i < 16; ++i) {
        const float d = v[i] - mu;
        var += d * d;
    }
    var *= (1.f / 16.f);
    const float rs = rsqrtf(var + 1e-5f);
#pragma unroll
    for (int i = 0; i < 16; ++i) v16[(size_t)row * 16 + i] = (v[i] - mu) * rs;
}

// ---------------------------------------------------------------------------
// kA7: Abf[row][i] = (v16[row][i&15]*g[i] + b[i]) * silu(z[row][i]), bf16.
// ---------------------------------------------------------------------------
__global__ __launch_bounds__(256) void kA7(const unsigned short* __restrict__ xz,
                                           const float* __restrict__ v16,
                                           const float* __restrict__ g,
                                           const float* __restrict__ bb,
                                           unsigned short* __restrict__ Abf) {
    const int row = blockIdx.x;
    const int t   = threadIdx.x;
    __shared__ float vrow[16];
    if (t < 16) vrow[t] = v16[row * 16 + t];
    __syncthreads();
    const int i0 = t * 8;
    const uint4 zraw = *(const uint4*)(xz + (size_t)row * NXZ_ + 2048 + i0);
    const unsigned short* zp = (const unsigned short*)&zraw;
    const float4 g0 = *(const float4*)(g + i0),  g1 = *(const float4*)(g + i0 + 4);
    const float4 b0 = *(const float4*)(bb + i0), b1 = *(const float4*)(bb + i0 + 4);
    const float gv[8] = {g0.x, g0.y, g0.z, g0.w, g1.x, g1.y, g1.z, g1.w};
    const float bv[8] = {b0.x, b0.y, b0.z, b0.w, b1.x, b1.y, b1.z, b1.w};
    unsigned short o[8];
#pragma unroll
    for (int j = 0; j < 8; ++j) {
        const int i = i0 + j;
        const float zf = bf2f(zp[j]);
        const float sz = zf / (1.f + expf(-zf));
        o[j] = f2bf((vrow[i & 15] * gv[j] + bv[j]) * sz);
    }
    *(uint4*)(Abf + (size_t)row * DI_ + i0) = *(const uint4*)o;
}

// ---------------------------------------------------------------------------
extern "C" void kernel_launch(void* const* d_in, const int* in_sizes, int n_in,
                              void* d_out, int out_size, void* d_ws, size_t ws_size,
                              hipStream_t stream) {
    const float* x    = (const float*)d_in[0];
    const float* Win  = (const float*)d_in[1];
    const float* Wcv  = (const float*)d_in[2];
    const float* Wxp  = (const float*)d_in[3];
    const float* Wdt  = (const float*)d_in[4];
    const float* bdt  = (const float*)d_in[5];
    const float* Wout = (const float*)d_in[6];
    const float* lng  = (const float*)d_in[7];
    const float* lnb  = (const float*)d_in[8];
    float* out = (float*)d_out;

    // ---- workspace layout (bytes), ~166 MB, lifetime-aliased ----
    char* base = (char*)d_ws;
    unsigned short* xz_bf   = (unsigned short*)(base + 0);           // 67.1 MB (k1->kA7)
    unsigned short* xsb     = (unsigned short*)(base + 67108864);    // 33.5 MB
    unsigned short* xbf     = (unsigned short*)(base + 100663296);   // 16.8 MB (dead after k1)
    unsigned short* Abf     = (unsigned short*)(base + 100663296);   // alias, 33.5 MB
    unsigned short* WoutT   = (unsigned short*)(base + 134217728);   // 4.2 MB
    unsigned short* WinT    = (unsigned short*)(base + 138412032);   // 8.4 MB
    unsigned short* WxpT    = (unsigned short*)(base + 146800640);   // 0.5 MB [128][2048]
    unsigned short* WdtT    = (unsigned short*)(base + 147324928);   // 0.26 MB [2048][64]
    float*          xp_part = (float*)(base + 147587072);            // 12.6 MB
    float*          xp      = (float*)(base + 160169984);            // 3.1 MB
    unsigned short* dtlo    = (unsigned short*)(base + 163315712);   // 1 MB [8192][64]
    float*          psum    = (float*)(base + 164364288);            // 0.5 MB [16][8192]
    float*          xm      = (float*)(base + 164888576);
    float*          dec     = (float*)(base + 164921344);
    float*          u       = (float*)(base + 164954112);
    float*          S       = (float*)(base + 164986880);
    float*          v16     = (float*)(base + 165019648);            // 0.5 MB

    kcvt<<<ROWS_ * D_ / 1024, 256, 0, stream>>>(x, xbf);
    ktrans<<<dim3(NXZ_ / 32, D_ / 32), 256, 0, stream>>>(Win, WinT, D_, NXZ_);
    ktrans<<<dim3(4, DI_ / 32), 256, 0, stream>>>(Wxp, WxpT, DI_, 96);
    ktrans<<<dim3(DI_ / 32, DTR_ / 32), 256, 0, stream>>>(Wdt, WdtT, DTR_, DI_);
    gemm256b<D_, true><<<dim3(ROWS_ / 256, NXZ_ / 128), 512, 0, stream>>>(
        xbf, WinT, xz_bf, NXZ_);
    ktrans<<<dim3(D_ / 32, DI_ / 32), 256, 0, stream>>>(Wout, WoutT, DI_, D_);
    k2_conv<<<ROWS_ / 16, 256, 0, stream>>>(xz_bf, Wcv, xsb, xm);
    k3m<<<dim3(ROWS_ / 128, 4), 256, 0, stream>>>(xsb, WxpT, xp_part);
    kred<<<ROWS_ * 96 / 4 / 256, 256, 0, stream>>>(xp_part, xp, dtlo);
    k4m<<<dim3(ROWS_ / 128, DI_ / 128), 256, 0, stream>>>(dtlo, WdtT, bdt, psum);
    k4r<<<ROWS_ / 256, 256, 0, stream>>>(psum, xp, xm, dec, u);
    k5_scan<<<1, 256, 0, stream>>>(dec, u, S);
    k6_v16<<<ROWS_ / 256, 256, 0, stream>>>(xp, S, v16);
    kA7<<<ROWS_, 256, 0, stream>>>(xz_bf, v16, lng, lnb, Abf);
    gemm256b<DI_, false><<<dim3(ROWS_ / 256, D_ / 128), 512, 0, stream>>>(
        Abf, WoutT, out, D_);
}